// Round 2
// baseline (4278.865 us; speedup 1.0000x reference)
//
#include <hip/hip_runtime.h>
#include <stdint.h>

typedef short short8 __attribute__((ext_vector_type(8)));
typedef float float4v __attribute__((ext_vector_type(4)));

#define NSTEPS 512

__device__ __forceinline__ unsigned short f2bf(float f) {
  unsigned u = __builtin_bit_cast(unsigned, f);
  u += 0x7fffu + ((u >> 16) & 1u);
  return (unsigned short)(u >> 16);
}

// xbf layout (A-fragment swizzled): short8[ ((l*4+g)*16 + kk)*64 + lane ]
// element (l, g, m, k):  m = lane&15, k = kk*32 + (lane>>4)*8 + j
__global__ __launch_bounds__(256) void xprep_kernel(const float* __restrict__ x,
                                                    short* __restrict__ xbf) {
  unsigned tid = blockIdx.x * 256u + threadIdx.x;   // 2,097,152 total
  unsigned lane = tid & 63u;
  unsigned kk   = (tid >> 6) & 15u;
  unsigned g    = (tid >> 10) & 3u;
  unsigned l    = tid >> 12;
  unsigned m = lane & 15u, qo = lane >> 4;
  const float* src = x + (((size_t)(g * 16u + m) * 512u + l) * 512u + kk * 32u + qo * 8u);
  float4 a  = ((const float4*)src)[0];
  float4 b2 = ((const float4*)src)[1];
  short8 v;
  v[0] = (short)f2bf(a.x);  v[1] = (short)f2bf(a.y);
  v[2] = (short)f2bf(a.z);  v[3] = (short)f2bf(a.w);
  v[4] = (short)f2bf(b2.x); v[5] = (short)f2bf(b2.y);
  v[6] = (short)f2bf(b2.z); v[7] = (short)f2bf(b2.w);
  *(short8*)(xbf + (size_t)tid * 8u) = v;
}

// Persistent recurrent kernel. PLAIN launch (no cooperative — cooperative
// launch is not graph-capturable and round-1 evidence says it never ran).
// Co-residency is structural: 128 blocks x 4 waves on 256 CUs.
// grid = 128: group g = (b&7)>>1 (16 sequences), chunk c = ((b>>3)<<1)|(b&1)
// (round-robin XCD heuristic: group g lands on XCDs {2g, 2g+1}).
// Wave w (0..3) owns gate type w (f,i,o,h), gate rows w*512 + c*16 + [0,16).
__global__ __launch_bounds__(256, 1) void lstm_persist(
    const float* __restrict__ Wfp, const float* __restrict__ bfp,
    const float* __restrict__ Wip, const float* __restrict__ bip,
    const float* __restrict__ Wop, const float* __restrict__ bop,
    const float* __restrict__ Whp, const float* __restrict__ bhp,
    const short* __restrict__ xbf,
    short* __restrict__ sbuf,        // [2][4][16kk][64lane][8] bf16 (A-swizzled)
    unsigned* __restrict__ arrive,   // [4][512]
    float* __restrict__ out)         // [64][512][512] fp32
{
  __shared__ float gl[4 * 16 * 17];  // [gate][seq][h(+pad)]

  const unsigned b = blockIdx.x;
  const unsigned g = (b & 7u) >> 1;
  const unsigned c = ((b >> 3) << 1) | (b & 1u);
  const unsigned t = threadIdx.x;
  const unsigned w = t >> 6;
  const unsigned lane = t & 63u;
  const unsigned m = lane & 15u, qo = lane >> 4;

  const float* Wsrc = (w == 0) ? Wfp : (w == 1) ? Wip : (w == 2) ? Wop : Whp;
  const float* bsrc = (w == 0) ? bfp : (w == 1) ? bip : (w == 2) ? bop : bhp;

  // ---- one-time: this wave's B-fragments (W rows c*16+[0,16)) into registers.
  // B[k][n]: n = lane&15 (gate row), k = kk*32 + qo*8 + j.
  short8 wsf[16], wnf[16];
  {
    const float* wrow = Wsrc + (size_t)(c * 16u + m) * 1024u + qo * 8u;
#pragma unroll
    for (int kk = 0; kk < 16; kk++) {
      const float* p = wrow + kk * 32;
      short8 vs, vn;
#pragma unroll
      for (int j = 0; j < 8; j++) {
        vs[j] = (short)f2bf(p[j]);          // W_short = cols [0,512)
        vn[j] = (short)f2bf(p[512 + j]);    // W_now   = cols [512,1024)
      }
      wsf[kk] = vs;
      wnf[kk] = vn;
    }
  }
  const float bias = bsrc[c * 16u + m];

  // elementwise ownership: thread t <-> (seq mm, h hh); state in register.
  const unsigned mm = t >> 4, hh = t & 15u;
  float longv = 0.f;
  float* outp = out + (size_t)(g * 16u + mm) * (512u * 512u) + (c * 16u + hh);

  for (int l = 0; l < NSTEPS; l++) {
    // ---- x-part: independent of peers, runs before the wait.
    const short8* xt = (const short8*)xbf + ((size_t)(l * 4 + g) * 16u) * 64u + lane;
    short8 xa[16];
#pragma unroll
    for (int kk = 0; kk < 16; kk++) xa[kk] = xt[(size_t)kk * 64u];

    float4v acc[4];
    {
      float4v bb = {bias, bias, bias, bias};
      float4v zz = {0.f, 0.f, 0.f, 0.f};
      acc[0] = bb; acc[1] = zz; acc[2] = zz; acc[3] = zz;
    }
#pragma unroll
    for (int kk = 0; kk < 16; kk++)
      acc[kk & 3] = __builtin_amdgcn_mfma_f32_16x16x32_bf16(xa[kk], wnf[kk], acc[kk & 3], 0, 0, 0);

    if (l > 0) {
      // ---- wait for all 32 chunks of this group to have posted step l-1.
      if (t == 0) {
        unsigned* flag = arrive + (size_t)g * NSTEPS + (unsigned)(l - 1);
        long spins = 0;
        while (__hip_atomic_load(flag, __ATOMIC_RELAXED, __HIP_MEMORY_SCOPE_AGENT) < 32u) {
          __builtin_amdgcn_s_sleep(2);
          if (++spins > (60LL * 1000 * 1000)) break;  // bail -> wrong, not hung
        }
      }
      __syncthreads();
      __builtin_amdgcn_fence(__ATOMIC_ACQUIRE, "agent");

      // ---- recurrent part: short^{l-1} A-fragments (coalesced 16B/lane).
      const short8* st = (const short8*)sbuf +
                         ((size_t)(((unsigned)(l - 1) & 1u) * 4u + g) * 16u) * 64u + lane;
      short8 sa[16];
#pragma unroll
      for (int kk = 0; kk < 16; kk++) sa[kk] = st[(size_t)kk * 64u];
#pragma unroll
      for (int kk = 0; kk < 16; kk++)
        acc[kk & 3] = __builtin_amdgcn_mfma_f32_16x16x32_bf16(sa[kk], wsf[kk], acc[kk & 3], 0, 0, 0);
    }

    float4v tot = (acc[0] + acc[1]) + (acc[2] + acc[3]);
    // C/D layout: col = lane&15 (gate row/h), row = qo*4 + r (seq)
#pragma unroll
    for (int r = 0; r < 4; r++)
      gl[(w * 16u + qo * 4u + (unsigned)r) * 17u + m] = tot[r];
    __syncthreads();

    // ---- elementwise update (all 256 threads: 16 seq x 16 h)
    float fg = gl[(0 * 16 + mm) * 17 + hh];
    float ig = gl[(1 * 16 + mm) * 17 + hh];
    float og = gl[(2 * 16 + mm) * 17 + hh];
    float hg = gl[(3 * 16 + mm) * 17 + hh];   // no activation on h (matches ref)
    fg = 1.f / (1.f + __expf(-fg));
    ig = 1.f / (1.f + __expf(-ig));
    og = 1.f / (1.f + __expf(-og));
    longv = fg * longv + ig * hg;
    float e  = __expf(-2.f * fabsf(longv));
    float th = (1.f - e) / (1.f + e);
    th = (longv < 0.f) ? -th : th;
    float sh = og * th;

    outp[(size_t)l * 512u] = sh;
    {
      // store bf16 short into A-swizzled sbuf slot for step l
      unsigned k   = c * 16u + hh;
      unsigned kk2 = k >> 5;
      unsigned lw  = ((k >> 3) & 3u) * 16u + mm;
      unsigned jj  = k & 7u;
      sbuf[((((size_t)((unsigned)l & 1u) * 4u + g) * 16u + kk2) * 64u + lw) * 8u + jj] =
          (short)f2bf(sh);
    }
    __syncthreads();  // drains all waves' stores (vmcnt(0) before s_barrier)
    if (t == 0)
      __hip_atomic_fetch_add(arrive + (size_t)g * NSTEPS + (unsigned)l, 1u,
                             __ATOMIC_RELEASE, __HIP_MEMORY_SCOPE_AGENT);
  }
}

extern "C" void kernel_launch(void* const* d_in, const int* in_sizes, int n_in,
                              void* d_out, int out_size, void* d_ws, size_t ws_size,
                              hipStream_t stream) {
  const float* x   = (const float*)d_in[0];
  const float* Wf  = (const float*)d_in[1];
  const float* bfv = (const float*)d_in[2];
  const float* Wi  = (const float*)d_in[3];
  const float* biv = (const float*)d_in[4];
  const float* Wo  = (const float*)d_in[5];
  const float* bov = (const float*)d_in[6];
  const float* Wh  = (const float*)d_in[7];
  const float* bhv = (const float*)d_in[8];
  float* out = (float*)d_out;

  char* ws = (char*)d_ws;
  short*    xbf    = (short*)ws;                                // 33,554,432 B
  short*    sbuf   = (short*)(ws + 33554432);                   //    131,072 B
  unsigned* arrive = (unsigned*)(ws + 33554432 + 131072);       //      8,192 B

  // zero the exchange buffer (initial short state = 0) and arrival counters
  hipMemsetAsync(ws + 33554432, 0, 131072 + 8192, stream);

  xprep_kernel<<<8192, 256, 0, stream>>>(x, xbf);

  lstm_persist<<<128, 256, 0, stream>>>(Wf, bfv, Wi, biv, Wo, bov, Wh, bhv,
                                        xbf, sbuf, arrive, out);
}

// Round 3
// 2102.225 us; speedup vs baseline: 2.0354x; 2.0354x over previous
//
#include <hip/hip_runtime.h>
#include <stdint.h>

typedef short short8 __attribute__((ext_vector_type(8)));
typedef float float4v __attribute__((ext_vector_type(4)));
typedef uint32_t u32;
typedef uint64_t u64;

#define NSTEPS 512

__device__ __forceinline__ unsigned short f2bf(float f) {
  unsigned u = __builtin_bit_cast(unsigned, f);
  u += 0x7fffu + ((u >> 16) & 1u);
  return (unsigned short)(u >> 16);
}

// xbf layout (A-fragment swizzled): short8[ ((l*4+g)*16 + kk)*64 + lane ]
// element (l, g, m, k):  m = lane&15, k = kk*32 + (lane>>4)*8 + j
__global__ __launch_bounds__(256) void xprep_kernel(const float* __restrict__ x,
                                                    short* __restrict__ xbf) {
  unsigned tid = blockIdx.x * 256u + threadIdx.x;   // 2,097,152 total
  unsigned lane = tid & 63u;
  unsigned kk   = (tid >> 6) & 15u;
  unsigned g    = (tid >> 10) & 3u;
  unsigned l    = tid >> 12;
  unsigned m = lane & 15u, qo = lane >> 4;
  const float* src = x + (((size_t)(g * 16u + m) * 512u + l) * 512u + kk * 32u + qo * 8u);
  float4 a  = ((const float4*)src)[0];
  float4 b2 = ((const float4*)src)[1];
  short8 v;
  v[0] = (short)f2bf(a.x);  v[1] = (short)f2bf(a.y);
  v[2] = (short)f2bf(a.z);  v[3] = (short)f2bf(a.w);
  v[4] = (short)f2bf(b2.x); v[5] = (short)f2bf(b2.y);
  v[6] = (short)f2bf(b2.z); v[7] = (short)f2bf(b2.w);
  *(short8*)(xbf + (size_t)tid * 8u) = v;
}

// Persistent recurrent kernel, fence-free sync protocol:
// ALL cross-block shared data (sbuf state + arrive flags) moves via
// agent-scope RELAXED atomics (sc1 -> coherent at Infinity Cache). No
// release/acquire fences -> no buffer_wbl2 / buffer_inv per step (round-2
// evidence: those fences made each step ~8 us).
// grid = 128: group g = (b&7)>>1 (16 sequences), chunk c = ((b>>3)<<1)|(b&1).
// Wave w (0..3) owns gate type w (f,i,o,h), gate rows w*512 + c*16 + [0,16).
__global__ __launch_bounds__(256, 1) void lstm_persist(
    const float* __restrict__ Wfp, const float* __restrict__ bfp,
    const float* __restrict__ Wip, const float* __restrict__ bip,
    const float* __restrict__ Wop, const float* __restrict__ bop,
    const float* __restrict__ Whp, const float* __restrict__ bhp,
    const short* __restrict__ xbf,
    short* __restrict__ sbuf,        // [2][4][16kk][64lane][8] bf16 (A-swizzled)
    u32* __restrict__ arrive,        // [4][32]: steps completed by chunk
    float* __restrict__ out)         // [64][512][512] fp32
{
  __shared__ float gl[4 * 16 * 17];  // [gate][seq][h(+pad)]

  const unsigned b = blockIdx.x;
  const unsigned g = (b & 7u) >> 1;
  const unsigned c = ((b >> 3) << 1) | (b & 1u);
  const unsigned t = threadIdx.x;
  const unsigned w = t >> 6;
  const unsigned lane = t & 63u;
  const unsigned m = lane & 15u, qo = lane >> 4;

  const float* Wsrc = (w == 0) ? Wfp : (w == 1) ? Wip : (w == 2) ? Wop : Whp;
  const float* bsrc = (w == 0) ? bfp : (w == 1) ? bip : (w == 2) ? bop : bhp;

  // ---- one-time: this wave's B-fragments (W rows c*16+[0,16)) into registers.
  // B[k][n]: n = lane&15 (gate row), k = kk*32 + qo*8 + j.
  short8 wsf[16], wnf[16];
  {
    const float* wrow = Wsrc + (size_t)(c * 16u + m) * 1024u + qo * 8u;
#pragma unroll
    for (int kk = 0; kk < 16; kk++) {
      const float* p = wrow + kk * 32;
      short8 vs, vn;
#pragma unroll
      for (int j = 0; j < 8; j++) {
        vs[j] = (short)f2bf(p[j]);          // W_short = cols [0,512)
        vn[j] = (short)f2bf(p[512 + j]);    // W_now   = cols [512,1024)
      }
      wsf[kk] = vs;
      wnf[kk] = vn;
    }
  }
  const float bias = bsrc[c * 16u + m];

  // elementwise ownership: thread t <-> (seq mm, h hh); state in register.
  const unsigned mm = t >> 4, hh = t & 15u;
  float longv = 0.f;
  float* outp = out + (size_t)(g * 16u + mm) * (512u * 512u) + (c * 16u + hh);

  // precomputed sbuf store slot (u32 = 2 adjacent bf16), even threads only
  u32* sdst;
  {
    unsigned k   = c * 16u + hh;       // hh even for storing threads
    unsigned kk2 = k >> 5;
    unsigned lw  = ((k >> 3) & 3u) * 16u + mm;
    unsigned jj  = k & 7u;
    sdst = (u32*)sbuf + ((((size_t)g) * 16u + kk2) * 64u + lw) * 4u + (jj >> 1);
  }
  const size_t sslot = (size_t)4u * 16u * 64u * 4u;  // u32s per buffer slot

  const u32* fl = arrive + g * 32u;

  for (int l = 0; l < NSTEPS; l++) {
    // ---- x-part: independent of peers, runs before the wait.
    const short8* xt = (const short8*)xbf + ((size_t)(l * 4 + g) * 16u) * 64u + lane;
    short8 xa[16];
#pragma unroll
    for (int kk = 0; kk < 16; kk++) xa[kk] = xt[(size_t)kk * 64u];

    float4v acc[4];
    {
      float4v bb = {bias, bias, bias, bias};
      float4v zz = {0.f, 0.f, 0.f, 0.f};
      acc[0] = bb; acc[1] = zz; acc[2] = zz; acc[3] = zz;
    }
#pragma unroll
    for (int kk = 0; kk < 16; kk++)
      acc[kk & 3] = __builtin_amdgcn_mfma_f32_16x16x32_bf16(xa[kk], wnf[kk], acc[kk & 3], 0, 0, 0);

    if (l > 0) {
      // ---- each wave independently waits for all 32 chunks to post step l-1.
      // One flag per lane, parallel divergent spin (no serialized RMWs).
      if (lane < 32u) {
        long spins = 0;
        while (__hip_atomic_load(fl + lane, __ATOMIC_RELAXED,
                                 __HIP_MEMORY_SCOPE_AGENT) < (u32)l) {
          __builtin_amdgcn_s_sleep(1);
          if (++spins > (100LL * 1000 * 1000)) break;  // bail -> wrong, not hung
        }
      }

      // ---- recurrent part: short^{l-1} A-fragments via coherent u64 loads.
      const u64* st = (const u64*)sbuf +
                      ((size_t)(((unsigned)(l - 1) & 1u) * 4u + g) * 16u) * 64u * 2u +
                      (size_t)lane * 2u;
      u64 tmp[32];
#pragma unroll
      for (int kk = 0; kk < 16; kk++) {
        tmp[2 * kk]     = __hip_atomic_load(st + (size_t)kk * 128u, __ATOMIC_RELAXED,
                                            __HIP_MEMORY_SCOPE_AGENT);
        tmp[2 * kk + 1] = __hip_atomic_load(st + (size_t)kk * 128u + 1u, __ATOMIC_RELAXED,
                                            __HIP_MEMORY_SCOPE_AGENT);
      }
#pragma unroll
      for (int kk = 0; kk < 16; kk++) {
        struct { u64 a, b; } p = { tmp[2 * kk], tmp[2 * kk + 1] };
        short8 sa = __builtin_bit_cast(short8, p);
        acc[kk & 3] = __builtin_amdgcn_mfma_f32_16x16x32_bf16(sa, wsf[kk], acc[kk & 3], 0, 0, 0);
      }
    }

    float4v tot = (acc[0] + acc[1]) + (acc[2] + acc[3]);
    // C/D layout: col = lane&15 (gate row/h), row = qo*4 + r (seq)
#pragma unroll
    for (int r = 0; r < 4; r++)
      gl[(w * 16u + qo * 4u + (unsigned)r) * 17u + m] = tot[r];
    __syncthreads();

    // ---- elementwise update (all 256 threads: 16 seq x 16 h)
    float fg = gl[(0 * 16 + mm) * 17 + hh];
    float ig = gl[(1 * 16 + mm) * 17 + hh];
    float og = gl[(2 * 16 + mm) * 17 + hh];
    float hg = gl[(3 * 16 + mm) * 17 + hh];   // no activation on h (matches ref)
    fg = 1.f / (1.f + __expf(-fg));
    ig = 1.f / (1.f + __expf(-ig));
    og = 1.f / (1.f + __expf(-og));
    longv = fg * longv + ig * hg;
    float e  = __expf(-2.f * fabsf(longv));
    float th = (1.f - e) / (1.f + e);
    th = (longv < 0.f) ? -th : th;
    float sh = og * th;

    // pack adjacent-h pair into u32, even threads store coherently (sc1)
    unsigned short mybf = f2bf(sh);
    float shn = __shfl_xor(sh, 1);
    if ((t & 1u) == 0u) {
      u32 val = (u32)mybf | ((u32)f2bf(shn) << 16);
      __hip_atomic_store(sdst + ((size_t)((unsigned)l & 1u)) * sslot, val,
                         __ATOMIC_RELAXED, __HIP_MEMORY_SCOPE_AGENT);
    }
    __syncthreads();  // vmcnt(0) drain of the sbuf stores before flag post
    if (t == 0)
      __hip_atomic_store((u32*)(arrive + g * 32u + c), (u32)(l + 1),
                         __ATOMIC_RELAXED, __HIP_MEMORY_SCOPE_AGENT);

    // output store AFTER the flag post: keeps it off the sync critical path
    outp[(size_t)l * 512u] = sh;
  }
}

extern "C" void kernel_launch(void* const* d_in, const int* in_sizes, int n_in,
                              void* d_out, int out_size, void* d_ws, size_t ws_size,
                              hipStream_t stream) {
  const float* x   = (const float*)d_in[0];
  const float* Wf  = (const float*)d_in[1];
  const float* bfv = (const float*)d_in[2];
  const float* Wi  = (const float*)d_in[3];
  const float* biv = (const float*)d_in[4];
  const float* Wo  = (const float*)d_in[5];
  const float* bov = (const float*)d_in[6];
  const float* Wh  = (const float*)d_in[7];
  const float* bhv = (const float*)d_in[8];
  float* out = (float*)d_out;

  char* ws = (char*)d_ws;
  short* xbf    = (short*)ws;                                // 33,554,432 B
  short* sbuf   = (short*)(ws + 33554432);                   //    131,072 B
  u32*   arrive = (u32*)(ws + 33554432 + 131072);            //        512 B

  // zero the arrival counters (sbuf needs no init: slot for step l is fully
  // written before anyone reads it; step 0 has no recurrent read)
  hipMemsetAsync(ws + 33554432 + 131072, 0, 512, stream);

  xprep_kernel<<<8192, 256, 0, stream>>>(x, xbf);

  lstm_persist<<<128, 256, 0, stream>>>(Wf, bfv, Wi, biv, Wo, bov, Wh, bhv,
                                        xbf, sbuf, arrive, out);
}